// Round 14
// baseline (222.769 us; speedup 1.0000x reference)
//
#include <hip/hip_runtime.h>

typedef unsigned short u16;
typedef _Float16 half8 __attribute__((ext_vector_type(8)));
typedef _Float16 h2 __attribute__((ext_vector_type(2)));
typedef float f32x4 __attribute__((ext_vector_type(4)));
typedef u16 u16x4 __attribute__((ext_vector_type(4)));
typedef u16 u16x8 __attribute__((ext_vector_type(8)));

#define MFMAH(a, b, c) __builtin_amdgcn_mfma_f32_16x16x32_f16(a, b, c, 0, 0, 0)

constexpr float LOG2E = 1.44269504088896f;
constexpr float THR = 12.0f;  // defer-max threshold in log2 units (p <= 2^12, fp16-safe)

__device__ __forceinline__ u16 f2h(float f) {
  _Float16 h = (_Float16)f;
  return __builtin_bit_cast(u16, h);
}
__device__ __forceinline__ h2 pkrtz(float a, float b) {
  return __builtin_bit_cast(h2, __builtin_amdgcn_cvt_pkrtz(a, b));
}
__device__ __forceinline__ void gload_lds16(const void* g, void* l) {
  __builtin_amdgcn_global_load_lds(
      (const __attribute__((address_space(1))) void*)g,
      (__attribute__((address_space(3))) void*)l,
      16, 0, 0);
}

// LDS tile swizzle for [128][32]-u16 tiles (64B rows): quarter q' = q ^ ((row>>1)&3).
__device__ __forceinline__ int swz(int row, int q) { return row * 32 + ((q ^ ((row >> 1) & 3)) << 3); }

// ---------------- fp32 -> fp16 conversion (weights only) ----------------
__device__ __forceinline__ void conv_block(const float* __restrict__ in,
                                           u16* __restrict__ out, int i) {
  const float4 a = reinterpret_cast<const float4*>(in)[2 * i];
  const float4 b = reinterpret_cast<const float4*>(in)[2 * i + 1];
  u16x8 o;
  o[0] = f2h(a.x); o[1] = f2h(a.y); o[2] = f2h(a.z); o[3] = f2h(a.w);
  o[4] = f2h(b.x); o[5] = f2h(b.y); o[6] = f2h(b.z); o[7] = f2h(b.w);
  reinterpret_cast<u16x8*>(out)[i] = o;
}

__global__ __launch_bounds__(256) void conv_w4(const float* __restrict__ w0,
                                               const float* __restrict__ w1,
                                               const float* __restrict__ w2,
                                               const float* __restrict__ w3,
                                               u16* __restrict__ o0, u16* __restrict__ o1,
                                               u16* __restrict__ o2, u16* __restrict__ o3,
                                               int n8) {
  int i = blockIdx.x * 256 + threadIdx.x;
  const int stride = gridDim.x * 256;
  for (; i < 4 * n8; i += stride) {
    const int sel = i / n8, j = i - sel * n8;
    if (sel == 0) conv_block(w0, o0, j);
    else if (sel == 1) conv_block(w1, o1, j);
    else if (sel == 2) conv_block(w2, o2, j);
    else conv_block(w3, o3, j);
  }
}

// ---------------- merged projection GEMM (Q,K,V; R12 2-buffer structure) ----------------
// Grid (8, 64, 3); tile 128x128, BK=32, double-buffered, one __syncthreads per step.
// z<2 epilogue: C-tile routed through LDS -> coalesced u16x8 stores.
__global__ __launch_bounds__(256) void proj_gemm(
    const float* __restrict__ Aq, const float* __restrict__ Ak, const float* __restrict__ Avv,
    const u16* __restrict__ Wq, const u16* __restrict__ Wk, const u16* __restrict__ Wv,
    const float* __restrict__ bq, const float* __restrict__ bk, const float* __restrict__ bv,
    u16* __restrict__ Cq, u16* __restrict__ Ck, u16* __restrict__ Cvv) {
  __shared__ u16 SH[4][4096];  // SH[0..1]=A bufs, SH[2..3]=B bufs; epilogue reuses all 32KB
  const int tid = threadIdx.x;
  const int lane = tid & 63, l16 = lane & 15, lhi = lane >> 4;
  const int wid = tid >> 6, wm = wid >> 1, wn = wid & 1;
  // XCD-panel colocation: all 8 bx of one (z,by) panel share one XCD (id%8).
  const int id = blockIdx.x + (blockIdx.y << 3) + (blockIdx.z << 9);
  const int xcd = id & 7;
  const int slot = id >> 3;
  const int by = ((slot & 7) << 3) | xcd;  // by % 8 == xcd
  const int rest = slot >> 3;
  const int bx = rest & 7;
  const int z = rest >> 3;
  const int bm0 = by * 128, bn0 = bx * 128;

  const float* Af = (z == 0) ? Aq : ((z == 1) ? Ak : Avv);
  const u16* Bw = (z == 0) ? Wq : ((z == 1) ? Wk : Wv);
  const float* bias = (z == 0) ? bq : ((z == 1) ? bk : bv);
  u16* C = (z == 0) ? Cq : ((z == 1) ? Ck : Cvv);
  const float scale = (z == 0) ? LOG2E : 1.0f;

  const int c0 = tid, c1 = tid + 256;
  const u16* Bg0 = Bw + (size_t)(bn0 + (c0 >> 2)) * 1024 + (((c0 & 3) ^ ((c0 >> 3) & 3)) << 3);
  const u16* Bg1 = Bw + (size_t)(bn0 + (c1 >> 2)) * 1024 + (((c1 & 3) ^ ((c1 >> 3) & 3)) << 3);
  const int arow = tid >> 2, aq = tid & 3;
  const float* Ar = Af + (size_t)(bm0 + arow) * 1024 + aq * 8;
  const int awoff = swz(arow, aq);  // same XOR for row and row+64

  f32x4 acc[4][4] = {};
  float4 an[4];

#define LOADA(kt)                                                          \
  do {                                                                     \
    an[0] = *reinterpret_cast<const float4*>(Ar + (kt));                   \
    an[1] = *reinterpret_cast<const float4*>(Ar + (kt) + 4);               \
    an[2] = *reinterpret_cast<const float4*>(Ar + (kt) + 64 * 1024);       \
    an[3] = *reinterpret_cast<const float4*>(Ar + (kt) + 64 * 1024 + 4);   \
  } while (0)
#define STAGEB(buf, kt)                                                    \
  do {                                                                     \
    gload_lds16(Bg0 + (kt), &SH[2 + (buf)][c0 * 8]);                       \
    gload_lds16(Bg1 + (kt), &SH[2 + (buf)][c1 * 8]);                       \
  } while (0)
#define WRITEA(buf)                                                        \
  do {                                                                     \
    union { u16x8 u; h2 h[4]; } w0_, w1_;                                  \
    w0_.h[0] = pkrtz(an[0].x, an[0].y); w0_.h[1] = pkrtz(an[0].z, an[0].w);\
    w0_.h[2] = pkrtz(an[1].x, an[1].y); w0_.h[3] = pkrtz(an[1].z, an[1].w);\
    w1_.h[0] = pkrtz(an[2].x, an[2].y); w1_.h[1] = pkrtz(an[2].z, an[2].w);\
    w1_.h[2] = pkrtz(an[3].x, an[3].y); w1_.h[3] = pkrtz(an[3].z, an[3].w);\
    u16* dst_ = &SH[buf][awoff];                                           \
    *reinterpret_cast<u16x8*>(dst_) = w0_.u;                               \
    *reinterpret_cast<u16x8*>(dst_ + 64 * 32) = w1_.u;                     \
  } while (0)

  LOADA(0);
  STAGEB(0, 0);
  WRITEA(0);
  __syncthreads();

  for (int ki = 0; ki < 32; ++ki) {
    const int cur = ki & 1, nxt = cur ^ 1;
    if (ki < 31) {
      LOADA((ki + 1) * 32);
      STAGEB(nxt, (ki + 1) * 32);
    }
    half8 af[4], bf[4];
#pragma unroll
    for (int f = 0; f < 4; ++f)
      af[f] = *reinterpret_cast<const half8*>(&SH[cur][swz(wm * 64 + f * 16 + l16, lhi)]);
#pragma unroll
    for (int f = 0; f < 4; ++f)
      bf[f] = *reinterpret_cast<const half8*>(&SH[2 + cur][swz(wn * 64 + f * 16 + l16, lhi)]);
#pragma unroll
    for (int i = 0; i < 4; ++i)
#pragma unroll
      for (int j = 0; j < 4; ++j)
        acc[i][j] = MFMAH(af[i], bf[j], acc[i][j]);
    if (ki < 31) WRITEA(nxt);
    __syncthreads();
  }
#undef LOADA
#undef STAGEB
#undef WRITEA

  if (z == 2) {
    // V: packed fragment-order stores (unchanged)
#pragma unroll
    for (int i = 0; i < 4; ++i) {
      const int m0 = bm0 + wm * 64 + i * 16 + lhi * 4;
#pragma unroll
      for (int j = 0; j < 4; ++j) {
        const int n = bn0 + wn * 64 + j * 16 + l16;
        const float bb = bias[n];
        u16x4 pack;
#pragma unroll
        for (int r = 0; r < 4; ++r) pack[r] = f2h(acc[i][j][r] + bb);
        const int head = (m0 >> 11) * 16 + (n >> 6);
        const int s0 = m0 & 2047;
        const int d = n & 63;
        const int within =
            ((s0 >> 5) & 1) * 2048 + d * 32 + ((s0 >> 2) & 3) * 8 + ((s0 >> 4) & 1) * 4;
        const int sw = within ^ ((d & 7) << 3);
        const size_t idx = (size_t)head * 131072 + (size_t)(s0 >> 6) * 4096 + sw;
        *reinterpret_cast<u16x4*>(&C[idx]) = pack;
      }
    }
  } else {
    // Q/K: route C-tile through LDS (reuse all 32KB) -> coalesced u16x8 stores
    u16* SF = &SH[0][0];  // flat 16384 u16 = [128][128]
#pragma unroll
    for (int i = 0; i < 4; ++i) {
      const int ml = wm * 64 + i * 16 + lhi * 4;
#pragma unroll
      for (int j = 0; j < 4; ++j) {
        const int nl = wn * 64 + j * 16 + l16;
        const float bb = bias[bn0 + nl];
#pragma unroll
        for (int r = 0; r < 4; ++r)
          SF[(ml + r) * 128 + nl] = f2h((acc[i][j][r] + bb) * scale);
      }
    }
    __syncthreads();
    const int t16 = tid & 15;
    const int hc = t16 >> 3;              // head half (0/1)
    const int d0 = (t16 & 7) * 8;         // d offset
#pragma unroll
    for (int p = 0; p < 8; ++p) {
      const int row = p * 16 + (tid >> 4);
      const u16x8 v = *reinterpret_cast<const u16x8*>(&SF[row * 128 + t16 * 8]);
      const int m = bm0 + row;
      const int bh = (m >> 11) * 16 + bx * 2 + hc;
      const size_t idx = ((size_t)bh * 2048 + (m & 2047)) * 64 + d0;
      *reinterpret_cast<u16x8*>(&C[idx]) = v;
    }
  }
}

// ---------------- output GEMM (R12 structure): X(fp16) @ Wo^T + bo -> f32 out ----------
__global__ __launch_bounds__(256) void out_gemm(const u16* __restrict__ A,
                                                const u16* __restrict__ Bw,
                                                const float* __restrict__ bias,
                                                float* __restrict__ C) {
  __shared__ u16 As[2][4096];
  __shared__ u16 Bs[2][4096];
  const int tid = threadIdx.x;
  const int lane = tid & 63, l16 = lane & 15, lhi = lane >> 4;
  const int wid = tid >> 6, wm = wid >> 1, wn = wid & 1;
  const int id = blockIdx.x + (blockIdx.y << 3);
  const int xcd = id & 7, slot = id >> 3;
  const int by = ((slot & 7) << 3) | xcd;
  const int bx = slot >> 3;
  const int bm0 = by * 128, bn0 = bx * 128;

  const int c0 = tid, c1 = tid + 256;
  const u16* Ag0 = A + (size_t)(bm0 + (c0 >> 2)) * 1024 + (((c0 & 3) ^ ((c0 >> 3) & 3)) << 3);
  const u16* Ag1 = A + (size_t)(bm0 + (c1 >> 2)) * 1024 + (((c1 & 3) ^ ((c1 >> 3) & 3)) << 3);
  const u16* Bg0 = Bw + (size_t)(bn0 + (c0 >> 2)) * 1024 + (((c0 & 3) ^ ((c0 >> 3) & 3)) << 3);
  const u16* Bg1 = Bw + (size_t)(bn0 + (c1 >> 2)) * 1024 + (((c1 & 3) ^ ((c1 >> 3) & 3)) << 3);

  f32x4 acc[4][4] = {};

#define STAGE16(buf, kt)                                  \
  do {                                                    \
    gload_lds16(Ag0 + (kt), &As[buf][c0 * 8]);            \
    gload_lds16(Ag1 + (kt), &As[buf][c1 * 8]);            \
    gload_lds16(Bg0 + (kt), &Bs[buf][c0 * 8]);            \
    gload_lds16(Bg1 + (kt), &Bs[buf][c1 * 8]);            \
  } while (0)

  STAGE16(0, 0);
  __syncthreads();
  for (int ki = 0; ki < 32; ++ki) {
    const int cur = ki & 1;
    if (ki < 31) STAGE16(cur ^ 1, (ki + 1) * 32);
    half8 af[4], bf[4];
#pragma unroll
    for (int f = 0; f < 4; ++f)
      af[f] = *reinterpret_cast<const half8*>(&As[cur][swz(wm * 64 + f * 16 + l16, lhi)]);
#pragma unroll
    for (int f = 0; f < 4; ++f)
      bf[f] = *reinterpret_cast<const half8*>(&Bs[cur][swz(wn * 64 + f * 16 + l16, lhi)]);
#pragma unroll
    for (int i = 0; i < 4; ++i)
#pragma unroll
      for (int j = 0; j < 4; ++j)
        acc[i][j] = MFMAH(af[i], bf[j], acc[i][j]);
    __syncthreads();
  }
#undef STAGE16

#pragma unroll
  for (int i = 0; i < 4; ++i) {
    const int m0 = bm0 + wm * 64 + i * 16 + lhi * 4;
#pragma unroll
    for (int j = 0; j < 4; ++j) {
      const int n = bn0 + wn * 64 + j * 16 + l16;
      const float bb = bias[n];
#pragma unroll
      for (int r = 0; r < 4; ++r)
        C[(size_t)(m0 + r) * 1024 + n] = acc[i][j][r] + bb;
    }
  }
  if (id == 0 && tid == 0) C[(size_t)8192 * 1024] = 0.0f;  // loss scalar
}

// ---------------- Flash attention (unchanged) ----------------
__global__ __launch_bounds__(256, 4) void attn_fwd(const u16* __restrict__ Q,
                                                   const u16* __restrict__ Kh,
                                                   const u16* __restrict__ VL,
                                                   u16* __restrict__ X) {
  __shared__ u16 Ks[2][4096];
  __shared__ u16 Vs[2][4096];

  const int tid = threadIdx.x, lane = tid & 63, w = tid >> 6;
  const int l16 = lane & 15, lhi = lane >> 4;
  const int blk = blockIdx.x;
  const int xcd = blk & 7, wi = blk >> 3;
  const int bh = (xcd << 3) | (wi >> 4);
  const int qt = wi & 15;
  const int b = bh >> 4, h = bh & 15;

  const size_t qrow0 = (size_t)bh * 2048 + qt * 128 + w * 32;
  half8 qf[2][2];
#pragma unroll
  for (int fq = 0; fq < 2; ++fq)
#pragma unroll
    for (int ks = 0; ks < 2; ++ks)
      qf[fq][ks] = *reinterpret_cast<const half8*>(
          &Q[(qrow0 + fq * 16 + l16) * 64 + ks * 32 + lhi * 8]);

  f32x4 o[2][4] = {};
  float mrow[2] = {-1e30f, -1e30f};
  float ssum[2] = {0.0f, 0.0f};

  const u16* Kb = Kh + (size_t)bh * 2048 * 64;
  const u16* VLh = VL + (size_t)bh * 64 * 64 * 32;

#define STAGE_KV(bufidx, tt)                                                      \
  do {                                                                            \
    const int kb0_ = (tt) * 64;                                                   \
    _Pragma("unroll")                                                             \
    for (int ii_ = 0; ii_ < 2; ++ii_) {                                           \
      const int c_ = tid + ii_ * 256;                                             \
      const int r_ = c_ >> 3, cb_ = c_ & 7;                                       \
      gload_lds16(Kb + (size_t)(kb0_ + r_) * 64 + ((cb_ ^ (r_ & 7)) << 3),        \
                  &Ks[bufidx][c_ * 8]);                                           \
      gload_lds16(VLh + (size_t)(tt) * 4096 + c_ * 8, &Vs[bufidx][c_ * 8]);       \
    }                                                                             \
  } while (0)

  STAGE_KV(0, 0);
  __syncthreads();

  for (int t = 0; t < 32; ++t) {
    const int cur = t & 1;
    if (t < 31) STAGE_KV(cur ^ 1, t + 1);
    f32x4 sc[2][4] = {};
    __builtin_amdgcn_s_setprio(1);
#pragma unroll
    for (int fk = 0; fk < 4; ++fk) {
      const int row = fk * 16 + l16;
#pragma unroll
      for (int ks = 0; ks < 2; ++ks) {
        const int off = (row * 64 + ks * 32 + lhi * 8) ^ ((row & 7) << 3);
        const half8 kf = *reinterpret_cast<const half8*>(&Ks[cur][off]);
#pragma unroll
        for (int fq = 0; fq < 2; ++fq) sc[fq][fk] = MFMAH(kf, qf[fq][ks], sc[fq][fk]);
      }
    }
    __builtin_amdgcn_s_setprio(0);
    float lm[2];
#pragma unroll
    for (int fq = 0; fq < 2; ++fq) {
      float a0 = fmaxf(fmaxf(sc[fq][0][0], sc[fq][0][1]), sc[fq][0][2]);
      float a1 = fmaxf(fmaxf(sc[fq][0][3], sc[fq][1][0]), sc[fq][1][1]);
      float a2 = fmaxf(fmaxf(sc[fq][1][2], sc[fq][1][3]), sc[fq][2][0]);
      float a3 = fmaxf(fmaxf(sc[fq][2][1], sc[fq][2][2]), sc[fq][2][3]);
      float a4 = fmaxf(fmaxf(sc[fq][3][0], sc[fq][3][1]), sc[fq][3][2]);
      float b0 = fmaxf(fmaxf(a0, a1), a2);
      float b1 = fmaxf(fmaxf(a3, a4), sc[fq][3][3]);
      lm[fq] = fmaxf(b0, b1);
    }
    const int trig = (lm[0] > mrow[0] + THR) || (lm[1] > mrow[1] + THR);
    if (__any(trig)) {
#pragma unroll
      for (int fq = 0; fq < 2; ++fq) {
        float rm = lm[fq];
        rm = fmaxf(rm, __shfl_xor(rm, 16));
        rm = fmaxf(rm, __shfl_xor(rm, 32));
        const float nm = fmaxf(mrow[fq], rm);
        const float scl = __builtin_amdgcn_exp2f(mrow[fq] - nm);
        mrow[fq] = nm;
        ssum[fq] *= scl;
        float sb[4];
#pragma unroll
        for (int r = 0; r < 4; ++r) sb[r] = __shfl(scl, lhi * 4 + r);
#pragma unroll
        for (int fd = 0; fd < 4; ++fd)
#pragma unroll
          for (int r = 0; r < 4; ++r) o[fq][fd][r] *= sb[r];
      }
    }
    half8 pa2[2][2];
#pragma unroll
    for (int fq = 0; fq < 2; ++fq) {
      union { half8 v[2]; h2 hh[8]; } uu;
#pragma unroll
      for (int fk = 0; fk < 4; ++fk) {
        const float p0 = __builtin_amdgcn_exp2f(sc[fq][fk][0] - mrow[fq]);
        const float p1 = __builtin_amdgcn_exp2f(sc[fq][fk][1] - mrow[fq]);
        const float p2 = __builtin_amdgcn_exp2f(sc[fq][fk][2] - mrow[fq]);
        const float p3 = __builtin_amdgcn_exp2f(sc[fq][fk][3] - mrow[fq]);
        ssum[fq] += (p0 + p1) + (p2 + p3);
        uu.hh[fk * 2 + 0] = pkrtz(p0, p1);
        uu.hh[fk * 2 + 1] = pkrtz(p2, p3);
      }
      pa2[fq][0] = uu.v[0];
      pa2[fq][1] = uu.v[1];
    }
    __builtin_amdgcn_s_setprio(1);
#pragma unroll
    for (int fd = 0; fd < 4; ++fd)
#pragma unroll
      for (int ts = 0; ts < 2; ++ts) {
        const int va = (ts * 2048 + (fd * 16 + l16) * 32 + lhi * 8) ^ ((l16 & 7) << 3);
        const half8 vf = *reinterpret_cast<const half8*>(&Vs[cur][va]);
#pragma unroll
        for (int fq = 0; fq < 2; ++fq) o[fq][fd] = MFMAH(pa2[fq][ts], vf, o[fq][fd]);
      }
    __builtin_amdgcn_s_setprio(0);
    __syncthreads();
  }
#undef STAGE_KV

#pragma unroll
  for (int fq = 0; fq < 2; ++fq) {
    float ss = ssum[fq];
    ss += __shfl_xor(ss, 16);
    ss += __shfl_xor(ss, 32);
    float iv[4];
#pragma unroll
    for (int r = 0; r < 4; ++r) iv[r] = 1.0f / __shfl(ss, lhi * 4 + r);
#pragma unroll
    for (int r = 0; r < 4; ++r) {
      const int q = qt * 128 + w * 32 + fq * 16 + lhi * 4 + r;
#pragma unroll
      for (int fd = 0; fd < 4; ++fd) {
        const int col = h * 64 + fd * 16 + l16;
        X[((size_t)b * 2048 + q) * 1024 + col] = f2h(o[fq][fd][r] * iv[r]);
      }
    }
  }
}

// ---------------- launch ----------------
extern "C" void kernel_launch(void* const* d_in, const int* in_sizes, int n_in,
                              void* d_out, int out_size, void* d_ws, size_t ws_size,
                              hipStream_t stream) {
  const float* q_f  = (const float*)d_in[0];
  const float* k_f  = (const float*)d_in[1];
  const float* v_f  = (const float*)d_in[2];
  const float* Wq_f = (const float*)d_in[4];
  const float* bq   = (const float*)d_in[5];
  const float* Wk_f = (const float*)d_in[6];
  const float* bk   = (const float*)d_in[7];
  const float* Wv_f = (const float*)d_in[8];
  const float* bv   = (const float*)d_in[9];
  const float* Wo_f = (const float*)d_in[10];
  const float* bo   = (const float*)d_in[11];

  const int SZ = 4 * 2048 * 1024;  // 8388608
  const int SW = 1024 * 1024;      // 1048576

  u16* ws = (u16*)d_ws;
  u16* wqb = ws;                 // fp16 weights
  u16* wkb = wqb + SW;
  u16* wvb = wkb + SW;
  u16* wob = wvb + SW;
  u16* Qb  = wob + SW;           // [B,H,S,D], pre-scaled by log2e
  u16* Kb  = Qb + SZ;            // [B,H,S,D]
  u16* VLb = Kb + SZ;            // swizzled fragment-order V
  u16* Xb  = VLb + SZ;           // [B,S,H*D]
  const size_t need_bytes = (size_t)(4 * SZ + 4 * SW) * 2;
  if (ws_size < need_bytes) return;

  conv_w4<<<1024, 256, 0, stream>>>(Wq_f, Wk_f, Wv_f, Wo_f, wqb, wkb, wvb, wob, SW / 8);

  proj_gemm<<<dim3(8, 64, 3), 256, 0, stream>>>(q_f, k_f, v_f, wqb, wkb, wvb,
                                                bq, bk, bv, Qb, Kb, VLb);

  attn_fwd<<<dim3(1024), 256, 0, stream>>>(Qb, Kb, VLb, Xb);

  out_gemm<<<dim3(8, 64), 256, 0, stream>>>(Xb, wob, bo, (float*)d_out);
}

// Round 15
// 210.283 us; speedup vs baseline: 1.0594x; 1.0594x over previous
//
#include <hip/hip_runtime.h>

typedef unsigned short u16;
typedef _Float16 half8 __attribute__((ext_vector_type(8)));
typedef _Float16 h2 __attribute__((ext_vector_type(2)));
typedef float f32x4 __attribute__((ext_vector_type(4)));
typedef u16 u16x4 __attribute__((ext_vector_type(4)));
typedef u16 u16x8 __attribute__((ext_vector_type(8)));

#define MFMAH(a, b, c) __builtin_amdgcn_mfma_f32_16x16x32_f16(a, b, c, 0, 0, 0)

constexpr float LOG2E = 1.44269504088896f;
constexpr float THR = 12.0f;  // defer-max threshold in log2 units (p <= 2^12, fp16-safe)

__device__ __forceinline__ u16 f2h(float f) {
  _Float16 h = (_Float16)f;
  return __builtin_bit_cast(u16, h);
}
__device__ __forceinline__ h2 pkrtz(float a, float b) {
  return __builtin_bit_cast(h2, __builtin_amdgcn_cvt_pkrtz(a, b));
}
__device__ __forceinline__ void gload_lds16(const void* g, void* l) {
  __builtin_amdgcn_global_load_lds(
      (const __attribute__((address_space(1))) void*)g,
      (__attribute__((address_space(3))) void*)l,
      16, 0, 0);
}

// LDS tile swizzle for [128][32]-u16 tiles (64B rows): quarter q' = q ^ ((row>>1)&3).
__device__ __forceinline__ int swz(int row, int q) { return row * 32 + ((q ^ ((row >> 1) & 3)) << 3); }

// ---------------- fp32 -> fp16 conversion (weights only) ----------------
__device__ __forceinline__ void conv_block(const float* __restrict__ in,
                                           u16* __restrict__ out, int i) {
  const float4 a = reinterpret_cast<const float4*>(in)[2 * i];
  const float4 b = reinterpret_cast<const float4*>(in)[2 * i + 1];
  u16x8 o;
  o[0] = f2h(a.x); o[1] = f2h(a.y); o[2] = f2h(a.z); o[3] = f2h(a.w);
  o[4] = f2h(b.x); o[5] = f2h(b.y); o[6] = f2h(b.z); o[7] = f2h(b.w);
  reinterpret_cast<u16x8*>(out)[i] = o;
}

__global__ __launch_bounds__(256) void conv_w4(const float* __restrict__ w0,
                                               const float* __restrict__ w1,
                                               const float* __restrict__ w2,
                                               const float* __restrict__ w3,
                                               u16* __restrict__ o0, u16* __restrict__ o1,
                                               u16* __restrict__ o2, u16* __restrict__ o3,
                                               int n8) {
  int i = blockIdx.x * 256 + threadIdx.x;
  const int stride = gridDim.x * 256;
  for (; i < 4 * n8; i += stride) {
    const int sel = i / n8, j = i - sel * n8;
    if (sel == 0) conv_block(w0, o0, j);
    else if (sel == 1) conv_block(w1, o1, j);
    else if (sel == 2) conv_block(w2, o2, j);
    else conv_block(w3, o3, j);
  }
}

// ---------------- merged projection GEMM (Q,K,V; R12 2-buffer structure) ----------------
// Grid (8, 64, 3); tile 128x128, BK=32, double-buffered, one __syncthreads per step.
__global__ __launch_bounds__(256) void proj_gemm(
    const float* __restrict__ Aq, const float* __restrict__ Ak, const float* __restrict__ Avv,
    const u16* __restrict__ Wq, const u16* __restrict__ Wk, const u16* __restrict__ Wv,
    const float* __restrict__ bq, const float* __restrict__ bk, const float* __restrict__ bv,
    u16* __restrict__ Cq, u16* __restrict__ Ck, u16* __restrict__ Cvv) {
  __shared__ u16 As[2][4096];
  __shared__ u16 Bs[2][4096];
  const int tid = threadIdx.x;
  const int lane = tid & 63, l16 = lane & 15, lhi = lane >> 4;
  const int wid = tid >> 6, wm = wid >> 1, wn = wid & 1;
  // XCD-panel colocation: all 8 bx of one (z,by) panel share one XCD (id%8).
  const int id = blockIdx.x + (blockIdx.y << 3) + (blockIdx.z << 9);
  const int xcd = id & 7;
  const int slot = id >> 3;
  const int by = ((slot & 7) << 3) | xcd;  // by % 8 == xcd
  const int rest = slot >> 3;
  const int bx = rest & 7;
  const int z = rest >> 3;
  const int bm0 = by * 128, bn0 = bx * 128;

  const float* Af = (z == 0) ? Aq : ((z == 1) ? Ak : Avv);
  const u16* Bw = (z == 0) ? Wq : ((z == 1) ? Wk : Wv);
  const float* bias = (z == 0) ? bq : ((z == 1) ? bk : bv);
  u16* C = (z == 0) ? Cq : ((z == 1) ? Ck : Cvv);
  const float scale = (z == 0) ? LOG2E : 1.0f;

  const int c0 = tid, c1 = tid + 256;
  const u16* Bg0 = Bw + (size_t)(bn0 + (c0 >> 2)) * 1024 + (((c0 & 3) ^ ((c0 >> 3) & 3)) << 3);
  const u16* Bg1 = Bw + (size_t)(bn0 + (c1 >> 2)) * 1024 + (((c1 & 3) ^ ((c1 >> 3) & 3)) << 3);
  const int arow = tid >> 2, aq = tid & 3;
  const float* Ar = Af + (size_t)(bm0 + arow) * 1024 + aq * 8;
  const int awoff = swz(arow, aq);  // same XOR for row and row+64

  f32x4 acc[4][4] = {};
  float4 an[4];

#define LOADA(kt)                                                          \
  do {                                                                     \
    an[0] = *reinterpret_cast<const float4*>(Ar + (kt));                   \
    an[1] = *reinterpret_cast<const float4*>(Ar + (kt) + 4);               \
    an[2] = *reinterpret_cast<const float4*>(Ar + (kt) + 64 * 1024);       \
    an[3] = *reinterpret_cast<const float4*>(Ar + (kt) + 64 * 1024 + 4);   \
  } while (0)
#define STAGEB(buf, kt)                                                    \
  do {                                                                     \
    gload_lds16(Bg0 + (kt), &Bs[buf][c0 * 8]);                             \
    gload_lds16(Bg1 + (kt), &Bs[buf][c1 * 8]);                             \
  } while (0)
#define WRITEA(buf)                                                        \
  do {                                                                     \
    union { u16x8 u; h2 h[4]; } w0_, w1_;                                  \
    w0_.h[0] = pkrtz(an[0].x, an[0].y); w0_.h[1] = pkrtz(an[0].z, an[0].w);\
    w0_.h[2] = pkrtz(an[1].x, an[1].y); w0_.h[3] = pkrtz(an[1].z, an[1].w);\
    w1_.h[0] = pkrtz(an[2].x, an[2].y); w1_.h[1] = pkrtz(an[2].z, an[2].w);\
    w1_.h[2] = pkrtz(an[3].x, an[3].y); w1_.h[3] = pkrtz(an[3].z, an[3].w);\
    u16* dst_ = &As[buf][awoff];                                           \
    *reinterpret_cast<u16x8*>(dst_) = w0_.u;                               \
    *reinterpret_cast<u16x8*>(dst_ + 64 * 32) = w1_.u;                     \
  } while (0)

  STAGEB(0, 0);
  LOADA(0);
  WRITEA(0);
  __syncthreads();

  for (int ki = 0; ki < 32; ++ki) {
    const int cur = ki & 1, nxt = cur ^ 1;
    if (ki < 31) {
      STAGEB(nxt, (ki + 1) * 32);  // issue the loads the barrier drains FIRST
      LOADA((ki + 1) * 32);
    }
    half8 af[4], bf[4];
#pragma unroll
    for (int f = 0; f < 4; ++f)
      af[f] = *reinterpret_cast<const half8*>(&As[cur][swz(wm * 64 + f * 16 + l16, lhi)]);
#pragma unroll
    for (int f = 0; f < 4; ++f)
      bf[f] = *reinterpret_cast<const half8*>(&Bs[cur][swz(wn * 64 + f * 16 + l16, lhi)]);
#pragma unroll
    for (int i = 0; i < 4; ++i)
#pragma unroll
      for (int j = 0; j < 4; ++j)
        acc[i][j] = MFMAH(af[i], bf[j], acc[i][j]);
    if (ki < 31) WRITEA(nxt);
    __syncthreads();
  }
#undef LOADA
#undef STAGEB
#undef WRITEA

#pragma unroll
  for (int i = 0; i < 4; ++i) {
    const int m0 = bm0 + wm * 64 + i * 16 + lhi * 4;
#pragma unroll
    for (int j = 0; j < 4; ++j) {
      const int n = bn0 + wn * 64 + j * 16 + l16;
      const float bb = bias[n];
      if (z == 2) {
        u16x4 pack;
#pragma unroll
        for (int r = 0; r < 4; ++r) pack[r] = f2h(acc[i][j][r] + bb);
        const int head = (m0 >> 11) * 16 + (n >> 6);
        const int s0 = m0 & 2047;
        const int d = n & 63;
        const int within =
            ((s0 >> 5) & 1) * 2048 + d * 32 + ((s0 >> 2) & 3) * 8 + ((s0 >> 4) & 1) * 4;
        const int sw = within ^ ((d & 7) << 3);
        const size_t idx = (size_t)head * 131072 + (size_t)(s0 >> 6) * 4096 + sw;
        *reinterpret_cast<u16x4*>(&C[idx]) = pack;
      } else {
#pragma unroll
        for (int r = 0; r < 4; ++r) {
          const int m = m0 + r;
          const size_t idx =
              ((size_t)((m >> 11) * 16 + (n >> 6)) * 2048 + (m & 2047)) * 64 + (n & 63);
          C[idx] = f2h((acc[i][j][r] + bb) * scale);
        }
      }
    }
  }
}

// ---------------- output GEMM (R12 structure): X(fp16) @ Wo^T + bo -> f32 out ----------
__global__ __launch_bounds__(256) void out_gemm(const u16* __restrict__ A,
                                                const u16* __restrict__ Bw,
                                                const float* __restrict__ bias,
                                                float* __restrict__ C) {
  __shared__ u16 As[2][4096];
  __shared__ u16 Bs[2][4096];
  const int tid = threadIdx.x;
  const int lane = tid & 63, l16 = lane & 15, lhi = lane >> 4;
  const int wid = tid >> 6, wm = wid >> 1, wn = wid & 1;
  const int id = blockIdx.x + (blockIdx.y << 3);
  const int xcd = id & 7, slot = id >> 3;
  const int by = ((slot & 7) << 3) | xcd;
  const int bx = slot >> 3;
  const int bm0 = by * 128, bn0 = bx * 128;

  const int c0 = tid, c1 = tid + 256;
  const u16* Ag0 = A + (size_t)(bm0 + (c0 >> 2)) * 1024 + (((c0 & 3) ^ ((c0 >> 3) & 3)) << 3);
  const u16* Ag1 = A + (size_t)(bm0 + (c1 >> 2)) * 1024 + (((c1 & 3) ^ ((c1 >> 3) & 3)) << 3);
  const u16* Bg0 = Bw + (size_t)(bn0 + (c0 >> 2)) * 1024 + (((c0 & 3) ^ ((c0 >> 3) & 3)) << 3);
  const u16* Bg1 = Bw + (size_t)(bn0 + (c1 >> 2)) * 1024 + (((c1 & 3) ^ ((c1 >> 3) & 3)) << 3);

  f32x4 acc[4][4] = {};

#define STAGE16(buf, kt)                                  \
  do {                                                    \
    gload_lds16(Ag0 + (kt), &As[buf][c0 * 8]);            \
    gload_lds16(Ag1 + (kt), &As[buf][c1 * 8]);            \
    gload_lds16(Bg0 + (kt), &Bs[buf][c0 * 8]);            \
    gload_lds16(Bg1 + (kt), &Bs[buf][c1 * 8]);            \
  } while (0)

  STAGE16(0, 0);
  __syncthreads();
  for (int ki = 0; ki < 32; ++ki) {
    const int cur = ki & 1;
    if (ki < 31) STAGE16(cur ^ 1, (ki + 1) * 32);
    half8 af[4], bf[4];
#pragma unroll
    for (int f = 0; f < 4; ++f)
      af[f] = *reinterpret_cast<const half8*>(&As[cur][swz(wm * 64 + f * 16 + l16, lhi)]);
#pragma unroll
    for (int f = 0; f < 4; ++f)
      bf[f] = *reinterpret_cast<const half8*>(&Bs[cur][swz(wn * 64 + f * 16 + l16, lhi)]);
#pragma unroll
    for (int i = 0; i < 4; ++i)
#pragma unroll
      for (int j = 0; j < 4; ++j)
        acc[i][j] = MFMAH(af[i], bf[j], acc[i][j]);
    __syncthreads();
  }
#undef STAGE16

#pragma unroll
  for (int i = 0; i < 4; ++i) {
    const int m0 = bm0 + wm * 64 + i * 16 + lhi * 4;
#pragma unroll
    for (int j = 0; j < 4; ++j) {
      const int n = bn0 + wn * 64 + j * 16 + l16;
      const float bb = bias[n];
#pragma unroll
      for (int r = 0; r < 4; ++r)
        C[(size_t)(m0 + r) * 1024 + n] = acc[i][j][r] + bb;
    }
  }
  if (id == 0 && tid == 0) C[(size_t)8192 * 1024] = 0.0f;  // loss scalar
}

// ---------------- Flash attention (unchanged) ----------------
__global__ __launch_bounds__(256, 4) void attn_fwd(const u16* __restrict__ Q,
                                                   const u16* __restrict__ Kh,
                                                   const u16* __restrict__ VL,
                                                   u16* __restrict__ X) {
  __shared__ u16 Ks[2][4096];
  __shared__ u16 Vs[2][4096];

  const int tid = threadIdx.x, lane = tid & 63, w = tid >> 6;
  const int l16 = lane & 15, lhi = lane >> 4;
  const int blk = blockIdx.x;
  const int xcd = blk & 7, wi = blk >> 3;
  const int bh = (xcd << 3) | (wi >> 4);
  const int qt = wi & 15;
  const int b = bh >> 4, h = bh & 15;

  const size_t qrow0 = (size_t)bh * 2048 + qt * 128 + w * 32;
  half8 qf[2][2];
#pragma unroll
  for (int fq = 0; fq < 2; ++fq)
#pragma unroll
    for (int ks = 0; ks < 2; ++ks)
      qf[fq][ks] = *reinterpret_cast<const half8*>(
          &Q[(qrow0 + fq * 16 + l16) * 64 + ks * 32 + lhi * 8]);

  f32x4 o[2][4] = {};
  float mrow[2] = {-1e30f, -1e30f};
  float ssum[2] = {0.0f, 0.0f};

  const u16* Kb = Kh + (size_t)bh * 2048 * 64;
  const u16* VLh = VL + (size_t)bh * 64 * 64 * 32;

#define STAGE_KV(bufidx, tt)                                                      \
  do {                                                                            \
    const int kb0_ = (tt) * 64;                                                   \
    _Pragma("unroll")                                                             \
    for (int ii_ = 0; ii_ < 2; ++ii_) {                                           \
      const int c_ = tid + ii_ * 256;                                             \
      const int r_ = c_ >> 3, cb_ = c_ & 7;                                       \
      gload_lds16(Kb + (size_t)(kb0_ + r_) * 64 + ((cb_ ^ (r_ & 7)) << 3),        \
                  &Ks[bufidx][c_ * 8]);                                           \
      gload_lds16(VLh + (size_t)(tt) * 4096 + c_ * 8, &Vs[bufidx][c_ * 8]);       \
    }                                                                             \
  } while (0)

  STAGE_KV(0, 0);
  __syncthreads();

  for (int t = 0; t < 32; ++t) {
    const int cur = t & 1;
    if (t < 31) STAGE_KV(cur ^ 1, t + 1);
    f32x4 sc[2][4] = {};
    __builtin_amdgcn_s_setprio(1);
#pragma unroll
    for (int fk = 0; fk < 4; ++fk) {
      const int row = fk * 16 + l16;
#pragma unroll
      for (int ks = 0; ks < 2; ++ks) {
        const int off = (row * 64 + ks * 32 + lhi * 8) ^ ((row & 7) << 3);
        const half8 kf = *reinterpret_cast<const half8*>(&Ks[cur][off]);
#pragma unroll
        for (int fq = 0; fq < 2; ++fq) sc[fq][fk] = MFMAH(kf, qf[fq][ks], sc[fq][fk]);
      }
    }
    __builtin_amdgcn_s_setprio(0);
    float lm[2];
#pragma unroll
    for (int fq = 0; fq < 2; ++fq) {
      float a0 = fmaxf(fmaxf(sc[fq][0][0], sc[fq][0][1]), sc[fq][0][2]);
      float a1 = fmaxf(fmaxf(sc[fq][0][3], sc[fq][1][0]), sc[fq][1][1]);
      float a2 = fmaxf(fmaxf(sc[fq][1][2], sc[fq][1][3]), sc[fq][2][0]);
      float a3 = fmaxf(fmaxf(sc[fq][2][1], sc[fq][2][2]), sc[fq][2][3]);
      float a4 = fmaxf(fmaxf(sc[fq][3][0], sc[fq][3][1]), sc[fq][3][2]);
      float b0 = fmaxf(fmaxf(a0, a1), a2);
      float b1 = fmaxf(fmaxf(a3, a4), sc[fq][3][3]);
      lm[fq] = fmaxf(b0, b1);
    }
    const int trig = (lm[0] > mrow[0] + THR) || (lm[1] > mrow[1] + THR);
    if (__any(trig)) {
#pragma unroll
      for (int fq = 0; fq < 2; ++fq) {
        float rm = lm[fq];
        rm = fmaxf(rm, __shfl_xor(rm, 16));
        rm = fmaxf(rm, __shfl_xor(rm, 32));
        const float nm = fmaxf(mrow[fq], rm);
        const float scl = __builtin_amdgcn_exp2f(mrow[fq] - nm);
        mrow[fq] = nm;
        ssum[fq] *= scl;
        float sb[4];
#pragma unroll
        for (int r = 0; r < 4; ++r) sb[r] = __shfl(scl, lhi * 4 + r);
#pragma unroll
        for (int fd = 0; fd < 4; ++fd)
#pragma unroll
          for (int r = 0; r < 4; ++r) o[fq][fd][r] *= sb[r];
      }
    }
    half8 pa2[2][2];
#pragma unroll
    for (int fq = 0; fq < 2; ++fq) {
      union { half8 v[2]; h2 hh[8]; } uu;
#pragma unroll
      for (int fk = 0; fk < 4; ++fk) {
        const float p0 = __builtin_amdgcn_exp2f(sc[fq][fk][0] - mrow[fq]);
        const float p1 = __builtin_amdgcn_exp2f(sc[fq][fk][1] - mrow[fq]);
        const float p2 = __builtin_amdgcn_exp2f(sc[fq][fk][2] - mrow[fq]);
        const float p3 = __builtin_amdgcn_exp2f(sc[fq][fk][3] - mrow[fq]);
        ssum[fq] += (p0 + p1) + (p2 + p3);
        uu.hh[fk * 2 + 0] = pkrtz(p0, p1);
        uu.hh[fk * 2 + 1] = pkrtz(p2, p3);
      }
      pa2[fq][0] = uu.v[0];
      pa2[fq][1] = uu.v[1];
    }
    __builtin_amdgcn_s_setprio(1);
#pragma unroll
    for (int fd = 0; fd < 4; ++fd)
#pragma unroll
      for (int ts = 0; ts < 2; ++ts) {
        const int va = (ts * 2048 + (fd * 16 + l16) * 32 + lhi * 8) ^ ((l16 & 7) << 3);
        const half8 vf = *reinterpret_cast<const half8*>(&Vs[cur][va]);
#pragma unroll
        for (int fq = 0; fq < 2; ++fq) o[fq][fd] = MFMAH(pa2[fq][ts], vf, o[fq][fd]);
      }
    __builtin_amdgcn_s_setprio(0);
    __syncthreads();
  }
#undef STAGE_KV

#pragma unroll
  for (int fq = 0; fq < 2; ++fq) {
    float ss = ssum[fq];
    ss += __shfl_xor(ss, 16);
    ss += __shfl_xor(ss, 32);
    float iv[4];
#pragma unroll
    for (int r = 0; r < 4; ++r) iv[r] = 1.0f / __shfl(ss, lhi * 4 + r);
#pragma unroll
    for (int r = 0; r < 4; ++r) {
      const int q = qt * 128 + w * 32 + fq * 16 + lhi * 4 + r;
#pragma unroll
      for (int fd = 0; fd < 4; ++fd) {
        const int col = h * 64 + fd * 16 + l16;
        X[((size_t)b * 2048 + q) * 1024 + col] = f2h(o[fq][fd][r] * iv[r]);
      }
    }
  }
}

// ---------------- launch ----------------
extern "C" void kernel_launch(void* const* d_in, const int* in_sizes, int n_in,
                              void* d_out, int out_size, void* d_ws, size_t ws_size,
                              hipStream_t stream) {
  const float* q_f  = (const float*)d_in[0];
  const float* k_f  = (const float*)d_in[1];
  const float* v_f  = (const float*)d_in[2];
  const float* Wq_f = (const float*)d_in[4];
  const float* bq   = (const float*)d_in[5];
  const float* Wk_f = (const float*)d_in[6];
  const float* bk   = (const float*)d_in[7];
  const float* Wv_f = (const float*)d_in[8];
  const float* bv   = (const float*)d_in[9];
  const float* Wo_f = (const float*)d_in[10];
  const float* bo   = (const float*)d_in[11];

  const int SZ = 4 * 2048 * 1024;  // 8388608
  const int SW = 1024 * 1024;      // 1048576

  u16* ws = (u16*)d_ws;
  u16* wqb = ws;                 // fp16 weights
  u16* wkb = wqb + SW;
  u16* wvb = wkb + SW;
  u16* wob = wvb + SW;
  u16* Qb  = wob + SW;           // [B,H,S,D], pre-scaled by log2e
  u16* Kb  = Qb + SZ;            // [B,H,S,D]
  u16* VLb = Kb + SZ;            // swizzled fragment-order V
  u16* Xb  = VLb + SZ;           // [B,S,H*D]
  const size_t need_bytes = (size_t)(4 * SZ + 4 * SW) * 2;
  if (ws_size < need_bytes) return;

  conv_w4<<<1024, 256, 0, stream>>>(Wq_f, Wk_f, Wv_f, Wo_f, wqb, wkb, wvb, wob, SW / 8);

  proj_gemm<<<dim3(8, 64, 3), 256, 0, stream>>>(q_f, k_f, v_f, wqb, wkb, wvb,
                                                bq, bk, bv, Qb, Kb, VLb);

  attn_fwd<<<dim3(1024), 256, 0, stream>>>(Qb, Kb, VLb, Xb);

  out_gemm<<<dim3(8, 64), 256, 0, stream>>>(Xb, wob, bo, (float*)d_out);
}

// Round 16
// 204.818 us; speedup vs baseline: 1.0876x; 1.0267x over previous
//
#include <hip/hip_runtime.h>

typedef unsigned short u16;
typedef _Float16 half8 __attribute__((ext_vector_type(8)));
typedef _Float16 h2 __attribute__((ext_vector_type(2)));
typedef float f32x4 __attribute__((ext_vector_type(4)));
typedef u16 u16x4 __attribute__((ext_vector_type(4)));
typedef u16 u16x8 __attribute__((ext_vector_type(8)));

#define MFMAH(a, b, c) __builtin_amdgcn_mfma_f32_16x16x32_f16(a, b, c, 0, 0, 0)

constexpr float LOG2E = 1.44269504088896f;
constexpr float THR = 12.0f;  // defer-max threshold in log2 units (p <= 2^12, fp16-safe)

__device__ __forceinline__ u16 f2h(float f) {
  _Float16 h = (_Float16)f;
  return __builtin_bit_cast(u16, h);
}
__device__ __forceinline__ h2 pkrtz(float a, float b) {
  return __builtin_bit_cast(h2, __builtin_amdgcn_cvt_pkrtz(a, b));
}
__device__ __forceinline__ void gload_lds16(const void* g, void* l) {
  __builtin_amdgcn_global_load_lds(
      (const __attribute__((address_space(1))) void*)g,
      (__attribute__((address_space(3))) void*)l,
      16, 0, 0);
}

// LDS tile swizzle for [128][32]-u16 tiles (64B rows): quarter q' = q ^ ((row>>1)&3).
__device__ __forceinline__ int swz(int row, int q) { return row * 32 + ((q ^ ((row >> 1) & 3)) << 3); }

// ---------------- fp32 -> fp16 conversion (weights only) ----------------
__device__ __forceinline__ void conv_block(const float* __restrict__ in,
                                           u16* __restrict__ out, int i) {
  const float4 a = reinterpret_cast<const float4*>(in)[2 * i];
  const float4 b = reinterpret_cast<const float4*>(in)[2 * i + 1];
  u16x8 o;
  o[0] = f2h(a.x); o[1] = f2h(a.y); o[2] = f2h(a.z); o[3] = f2h(a.w);
  o[4] = f2h(b.x); o[5] = f2h(b.y); o[6] = f2h(b.z); o[7] = f2h(b.w);
  reinterpret_cast<u16x8*>(out)[i] = o;
}

__global__ __launch_bounds__(256) void conv_w4(const float* __restrict__ w0,
                                               const float* __restrict__ w1,
                                               const float* __restrict__ w2,
                                               const float* __restrict__ w3,
                                               u16* __restrict__ o0, u16* __restrict__ o1,
                                               u16* __restrict__ o2, u16* __restrict__ o3,
                                               int n8) {
  int i = blockIdx.x * 256 + threadIdx.x;
  const int stride = gridDim.x * 256;
  for (; i < 4 * n8; i += stride) {
    const int sel = i / n8, j = i - sel * n8;
    if (sel == 0) conv_block(w0, o0, j);
    else if (sel == 1) conv_block(w1, o1, j);
    else if (sel == 2) conv_block(w2, o2, j);
    else conv_block(w3, o3, j);
  }
}

// ---------------- merged projection GEMM (Q,K,V; R12 2-buffer structure) ----------------
// Grid (8, 64, 3); tile 128x128, BK=32, double-buffered, one __syncthreads per step.
__global__ __launch_bounds__(256) void proj_gemm(
    const float* __restrict__ Aq, const float* __restrict__ Ak, const float* __restrict__ Avv,
    const u16* __restrict__ Wq, const u16* __restrict__ Wk, const u16* __restrict__ Wv,
    const float* __restrict__ bq, const float* __restrict__ bk, const float* __restrict__ bv,
    u16* __restrict__ Cq, u16* __restrict__ Ck, u16* __restrict__ Cvv) {
  __shared__ u16 As[2][4096];
  __shared__ u16 Bs[2][4096];
  const int tid = threadIdx.x;
  const int lane = tid & 63, l16 = lane & 15, lhi = lane >> 4;
  const int wid = tid >> 6, wm = wid >> 1, wn = wid & 1;
  // XCD-panel colocation: all 8 bx of one (z,by) panel share one XCD (id%8).
  const int id = blockIdx.x + (blockIdx.y << 3) + (blockIdx.z << 9);
  const int xcd = id & 7;
  const int slot = id >> 3;
  const int by = ((slot & 7) << 3) | xcd;  // by % 8 == xcd
  const int rest = slot >> 3;
  const int bx = rest & 7;
  const int z = rest >> 3;
  const int bm0 = by * 128, bn0 = bx * 128;

  const float* Af = (z == 0) ? Aq : ((z == 1) ? Ak : Avv);
  const u16* Bw = (z == 0) ? Wq : ((z == 1) ? Wk : Wv);
  const float* bias = (z == 0) ? bq : ((z == 1) ? bk : bv);
  u16* C = (z == 0) ? Cq : ((z == 1) ? Ck : Cvv);
  const float scale = (z == 0) ? LOG2E : 1.0f;

  const int c0 = tid, c1 = tid + 256;
  const u16* Bg0 = Bw + (size_t)(bn0 + (c0 >> 2)) * 1024 + (((c0 & 3) ^ ((c0 >> 3) & 3)) << 3);
  const u16* Bg1 = Bw + (size_t)(bn0 + (c1 >> 2)) * 1024 + (((c1 & 3) ^ ((c1 >> 3) & 3)) << 3);
  const int arow = tid >> 2, aq = tid & 3;
  const float* Ar = Af + (size_t)(bm0 + arow) * 1024 + aq * 8;
  const int awoff = swz(arow, aq);  // same XOR for row and row+64

  f32x4 acc[4][4] = {};
  float4 an[4];

#define LOADA(kt)                                                          \
  do {                                                                     \
    an[0] = *reinterpret_cast<const float4*>(Ar + (kt));                   \
    an[1] = *reinterpret_cast<const float4*>(Ar + (kt) + 4);               \
    an[2] = *reinterpret_cast<const float4*>(Ar + (kt) + 64 * 1024);       \
    an[3] = *reinterpret_cast<const float4*>(Ar + (kt) + 64 * 1024 + 4);   \
  } while (0)
#define STAGEB(buf, kt)                                                    \
  do {                                                                     \
    gload_lds16(Bg0 + (kt), &Bs[buf][c0 * 8]);                             \
    gload_lds16(Bg1 + (kt), &Bs[buf][c1 * 8]);                             \
  } while (0)
#define WRITEA(buf)                                                        \
  do {                                                                     \
    union { u16x8 u; h2 h[4]; } w0_, w1_;                                  \
    w0_.h[0] = pkrtz(an[0].x, an[0].y); w0_.h[1] = pkrtz(an[0].z, an[0].w);\
    w0_.h[2] = pkrtz(an[1].x, an[1].y); w0_.h[3] = pkrtz(an[1].z, an[1].w);\
    w1_.h[0] = pkrtz(an[2].x, an[2].y); w1_.h[1] = pkrtz(an[2].z, an[2].w);\
    w1_.h[2] = pkrtz(an[3].x, an[3].y); w1_.h[3] = pkrtz(an[3].z, an[3].w);\
    u16* dst_ = &As[buf][awoff];                                           \
    *reinterpret_cast<u16x8*>(dst_) = w0_.u;                               \
    *reinterpret_cast<u16x8*>(dst_ + 64 * 32) = w1_.u;                     \
  } while (0)

  STAGEB(0, 0);
  LOADA(0);
  WRITEA(0);
  __syncthreads();

  for (int ki = 0; ki < 32; ++ki) {
    const int cur = ki & 1, nxt = cur ^ 1;
    if (ki < 31) {
      STAGEB(nxt, (ki + 1) * 32);  // issue the loads the barrier drains FIRST
      LOADA((ki + 1) * 32);
    }
    half8 af[4], bf[4];
#pragma unroll
    for (int f = 0; f < 4; ++f)
      af[f] = *reinterpret_cast<const half8*>(&As[cur][swz(wm * 64 + f * 16 + l16, lhi)]);
#pragma unroll
    for (int f = 0; f < 4; ++f)
      bf[f] = *reinterpret_cast<const half8*>(&Bs[cur][swz(wn * 64 + f * 16 + l16, lhi)]);
#pragma unroll
    for (int i = 0; i < 4; ++i)
#pragma unroll
      for (int j = 0; j < 4; ++j)
        acc[i][j] = MFMAH(af[i], bf[j], acc[i][j]);
    if (ki < 31) WRITEA(nxt);
    __syncthreads();
  }
#undef LOADA
#undef STAGEB
#undef WRITEA

#pragma unroll
  for (int i = 0; i < 4; ++i) {
    const int m0 = bm0 + wm * 64 + i * 16 + lhi * 4;
#pragma unroll
    for (int j = 0; j < 4; ++j) {
      const int n = bn0 + wn * 64 + j * 16 + l16;
      const float bb = bias[n];
      if (z == 2) {
        u16x4 pack;
#pragma unroll
        for (int r = 0; r < 4; ++r) pack[r] = f2h(acc[i][j][r] + bb);
        const int head = (m0 >> 11) * 16 + (n >> 6);
        const int s0 = m0 & 2047;
        const int d = n & 63;
        const int within =
            ((s0 >> 5) & 1) * 2048 + d * 32 + ((s0 >> 2) & 3) * 8 + ((s0 >> 4) & 1) * 4;
        const int sw = within ^ ((d & 7) << 3);
        const size_t idx = (size_t)head * 131072 + (size_t)(s0 >> 6) * 4096 + sw;
        *reinterpret_cast<u16x4*>(&C[idx]) = pack;
      } else {
#pragma unroll
        for (int r = 0; r < 4; ++r) {
          const int m = m0 + r;
          const size_t idx =
              ((size_t)((m >> 11) * 16 + (n >> 6)) * 2048 + (m & 2047)) * 64 + (n & 63);
          C[idx] = f2h((acc[i][j][r] + bb) * scale);
        }
      }
    }
  }
}

// ---------------- output GEMM (R12 structure): X(fp16) @ Wo^T + bo -> f32 out ----------
__global__ __launch_bounds__(256) void out_gemm(const u16* __restrict__ A,
                                                const u16* __restrict__ Bw,
                                                const float* __restrict__ bias,
                                                float* __restrict__ C) {
  __shared__ u16 As[2][4096];
  __shared__ u16 Bs[2][4096];
  const int tid = threadIdx.x;
  const int lane = tid & 63, l16 = lane & 15, lhi = lane >> 4;
  const int wid = tid >> 6, wm = wid >> 1, wn = wid & 1;
  const int id = blockIdx.x + (blockIdx.y << 3);
  const int xcd = id & 7, slot = id >> 3;
  const int by = ((slot & 7) << 3) | xcd;
  const int bx = slot >> 3;
  const int bm0 = by * 128, bn0 = bx * 128;

  const int c0 = tid, c1 = tid + 256;
  const u16* Ag0 = A + (size_t)(bm0 + (c0 >> 2)) * 1024 + (((c0 & 3) ^ ((c0 >> 3) & 3)) << 3);
  const u16* Ag1 = A + (size_t)(bm0 + (c1 >> 2)) * 1024 + (((c1 & 3) ^ ((c1 >> 3) & 3)) << 3);
  const u16* Bg0 = Bw + (size_t)(bn0 + (c0 >> 2)) * 1024 + (((c0 & 3) ^ ((c0 >> 3) & 3)) << 3);
  const u16* Bg1 = Bw + (size_t)(bn0 + (c1 >> 2)) * 1024 + (((c1 & 3) ^ ((c1 >> 3) & 3)) << 3);

  f32x4 acc[4][4] = {};

#define STAGE16(buf, kt)                                  \
  do {                                                    \
    gload_lds16(Ag0 + (kt), &As[buf][c0 * 8]);            \
    gload_lds16(Ag1 + (kt), &As[buf][c1 * 8]);            \
    gload_lds16(Bg0 + (kt), &Bs[buf][c0 * 8]);            \
    gload_lds16(Bg1 + (kt), &Bs[buf][c1 * 8]);            \
  } while (0)

  STAGE16(0, 0);
  __syncthreads();
  for (int ki = 0; ki < 32; ++ki) {
    const int cur = ki & 1;
    if (ki < 31) STAGE16(cur ^ 1, (ki + 1) * 32);
    half8 af[4], bf[4];
#pragma unroll
    for (int f = 0; f < 4; ++f)
      af[f] = *reinterpret_cast<const half8*>(&As[cur][swz(wm * 64 + f * 16 + l16, lhi)]);
#pragma unroll
    for (int f = 0; f < 4; ++f)
      bf[f] = *reinterpret_cast<const half8*>(&Bs[cur][swz(wn * 64 + f * 16 + l16, lhi)]);
#pragma unroll
    for (int i = 0; i < 4; ++i)
#pragma unroll
      for (int j = 0; j < 4; ++j)
        acc[i][j] = MFMAH(af[i], bf[j], acc[i][j]);
    __syncthreads();
  }
#undef STAGE16

#pragma unroll
  for (int i = 0; i < 4; ++i) {
    const int m0 = bm0 + wm * 64 + i * 16 + lhi * 4;
#pragma unroll
    for (int j = 0; j < 4; ++j) {
      const int n = bn0 + wn * 64 + j * 16 + l16;
      const float bb = bias[n];
#pragma unroll
      for (int r = 0; r < 4; ++r)
        C[(size_t)(m0 + r) * 1024 + n] = acc[i][j][r] + bb;
    }
  }
  if (id == 0 && tid == 0) C[(size_t)8192 * 1024] = 0.0f;  // loss scalar
}

// ---------------- Flash attention: 8-wave blocks (256 q-rows), halved staging ----------
// Grid 512, 512 threads. Per-wave arithmetic identical to R15; K/V staged once per
// 256 q-rows (2 gload_lds/thread/tile instead of 4). XCD colocation: 8 blocks/head.
__global__ __launch_bounds__(512, 4) void attn_fwd(const u16* __restrict__ Q,
                                                   const u16* __restrict__ Kh,
                                                   const u16* __restrict__ VL,
                                                   u16* __restrict__ X) {
  __shared__ u16 Ks[2][4096];
  __shared__ u16 Vs[2][4096];

  const int tid = threadIdx.x, lane = tid & 63, w = tid >> 6;
  const int l16 = lane & 15, lhi = lane >> 4;
  const int blk = blockIdx.x;
  const int xcd = blk & 7, wi = blk >> 3;   // wi 0..63
  const int bh = (xcd << 3) | (wi >> 3);    // 8 consecutive heads per XCD
  const int qt8 = wi & 7;                   // 8 blocks of 256 q-rows per head
  const int b = bh >> 4, h = bh & 15;

  const size_t qrow0 = (size_t)bh * 2048 + qt8 * 256 + w * 32;
  half8 qf[2][2];
#pragma unroll
  for (int fq = 0; fq < 2; ++fq)
#pragma unroll
    for (int ks = 0; ks < 2; ++ks)
      qf[fq][ks] = *reinterpret_cast<const half8*>(
          &Q[(qrow0 + fq * 16 + l16) * 64 + ks * 32 + lhi * 8]);

  f32x4 o[2][4] = {};
  float mrow[2] = {-1e30f, -1e30f};
  float ssum[2] = {0.0f, 0.0f};

  const u16* Kb = Kh + (size_t)bh * 2048 * 64;
  const u16* VLh = VL + (size_t)bh * 64 * 64 * 32;

#define STAGE_KV(bufidx, tt)                                                      \
  do {                                                                            \
    const int kb0_ = (tt) * 64;                                                   \
    const int r_ = tid >> 3, cb_ = tid & 7;                                       \
    gload_lds16(Kb + (size_t)(kb0_ + r_) * 64 + ((cb_ ^ (r_ & 7)) << 3),          \
                &Ks[bufidx][tid * 8]);                                            \
    gload_lds16(VLh + (size_t)(tt) * 4096 + tid * 8, &Vs[bufidx][tid * 8]);       \
  } while (0)

  STAGE_KV(0, 0);
  __syncthreads();

  for (int t = 0; t < 32; ++t) {
    const int cur = t & 1;
    if (t < 31) STAGE_KV(cur ^ 1, t + 1);
    f32x4 sc[2][4] = {};
    __builtin_amdgcn_s_setprio(1);
#pragma unroll
    for (int fk = 0; fk < 4; ++fk) {
      const int row = fk * 16 + l16;
#pragma unroll
      for (int ks = 0; ks < 2; ++ks) {
        const int off = (row * 64 + ks * 32 + lhi * 8) ^ ((row & 7) << 3);
        const half8 kf = *reinterpret_cast<const half8*>(&Ks[cur][off]);
#pragma unroll
        for (int fq = 0; fq < 2; ++fq) sc[fq][fk] = MFMAH(kf, qf[fq][ks], sc[fq][fk]);
      }
    }
    __builtin_amdgcn_s_setprio(0);
    float lm[2];
#pragma unroll
    for (int fq = 0; fq < 2; ++fq) {
      float a0 = fmaxf(fmaxf(sc[fq][0][0], sc[fq][0][1]), sc[fq][0][2]);
      float a1 = fmaxf(fmaxf(sc[fq][0][3], sc[fq][1][0]), sc[fq][1][1]);
      float a2 = fmaxf(fmaxf(sc[fq][1][2], sc[fq][1][3]), sc[fq][2][0]);
      float a3 = fmaxf(fmaxf(sc[fq][2][1], sc[fq][2][2]), sc[fq][2][3]);
      float a4 = fmaxf(fmaxf(sc[fq][3][0], sc[fq][3][1]), sc[fq][3][2]);
      float b0 = fmaxf(fmaxf(a0, a1), a2);
      float b1 = fmaxf(fmaxf(a3, a4), sc[fq][3][3]);
      lm[fq] = fmaxf(b0, b1);
    }
    const int trig = (lm[0] > mrow[0] + THR) || (lm[1] > mrow[1] + THR);
    if (__any(trig)) {
#pragma unroll
      for (int fq = 0; fq < 2; ++fq) {
        float rm = lm[fq];
        rm = fmaxf(rm, __shfl_xor(rm, 16));
        rm = fmaxf(rm, __shfl_xor(rm, 32));
        const float nm = fmaxf(mrow[fq], rm);
        const float scl = __builtin_amdgcn_exp2f(mrow[fq] - nm);
        mrow[fq] = nm;
        ssum[fq] *= scl;
        float sb[4];
#pragma unroll
        for (int r = 0; r < 4; ++r) sb[r] = __shfl(scl, lhi * 4 + r);
#pragma unroll
        for (int fd = 0; fd < 4; ++fd)
#pragma unroll
          for (int r = 0; r < 4; ++r) o[fq][fd][r] *= sb[r];
      }
    }
    half8 pa2[2][2];
#pragma unroll
    for (int fq = 0; fq < 2; ++fq) {
      union { half8 v[2]; h2 hh[8]; } uu;
#pragma unroll
      for (int fk = 0; fk < 4; ++fk) {
        const float p0 = __builtin_amdgcn_exp2f(sc[fq][fk][0] - mrow[fq]);
        const float p1 = __builtin_amdgcn_exp2f(sc[fq][fk][1] - mrow[fq]);
        const float p2 = __builtin_amdgcn_exp2f(sc[fq][fk][2] - mrow[fq]);
        const float p3 = __builtin_amdgcn_exp2f(sc[fq][fk][3] - mrow[fq]);
        ssum[fq] += (p0 + p1) + (p2 + p3);
        uu.hh[fk * 2 + 0] = pkrtz(p0, p1);
        uu.hh[fk * 2 + 1] = pkrtz(p2, p3);
      }
      pa2[fq][0] = uu.v[0];
      pa2[fq][1] = uu.v[1];
    }
    __builtin_amdgcn_s_setprio(1);
#pragma unroll
    for (int fd = 0; fd < 4; ++fd)
#pragma unroll
      for (int ts = 0; ts < 2; ++ts) {
        const int va = (ts * 2048 + (fd * 16 + l16) * 32 + lhi * 8) ^ ((l16 & 7) << 3);
        const half8 vf = *reinterpret_cast<const half8*>(&Vs[cur][va]);
#pragma unroll
        for (int fq = 0; fq < 2; ++fq) o[fq][fd] = MFMAH(pa2[fq][ts], vf, o[fq][fd]);
      }
    __builtin_amdgcn_s_setprio(0);
    __syncthreads();
  }
#undef STAGE_KV

#pragma unroll
  for (int fq = 0; fq < 2; ++fq) {
    float ss = ssum[fq];
    ss += __shfl_xor(ss, 16);
    ss += __shfl_xor(ss, 32);
    float iv[4];
#pragma unroll
    for (int r = 0; r < 4; ++r) iv[r] = 1.0f / __shfl(ss, lhi * 4 + r);
#pragma unroll
    for (int r = 0; r < 4; ++r) {
      const int q = qt8 * 256 + w * 32 + fq * 16 + lhi * 4 + r;
#pragma unroll
      for (int fd = 0; fd < 4; ++fd) {
        const int col = h * 64 + fd * 16 + l16;
        X[((size_t)b * 2048 + q) * 1024 + col] = f2h(o[fq][fd][r] * iv[r]);
      }
    }
  }
}

// ---------------- launch ----------------
extern "C" void kernel_launch(void* const* d_in, const int* in_sizes, int n_in,
                              void* d_out, int out_size, void* d_ws, size_t ws_size,
                              hipStream_t stream) {
  const float* q_f  = (const float*)d_in[0];
  const float* k_f  = (const float*)d_in[1];
  const float* v_f  = (const float*)d_in[2];
  const float* Wq_f = (const float*)d_in[4];
  const float* bq   = (const float*)d_in[5];
  const float* Wk_f = (const float*)d_in[6];
  const float* bk   = (const float*)d_in[7];
  const float* Wv_f = (const float*)d_in[8];
  const float* bv   = (const float*)d_in[9];
  const float* Wo_f = (const float*)d_in[10];
  const float* bo   = (const float*)d_in[11];

  const int SZ = 4 * 2048 * 1024;  // 8388608
  const int SW = 1024 * 1024;      // 1048576

  u16* ws = (u16*)d_ws;
  u16* wqb = ws;                 // fp16 weights
  u16* wkb = wqb + SW;
  u16* wvb = wkb + SW;
  u16* wob = wvb + SW;
  u16* Qb  = wob + SW;           // [B,H,S,D], pre-scaled by log2e
  u16* Kb  = Qb + SZ;            // [B,H,S,D]
  u16* VLb = Kb + SZ;            // swizzled fragment-order V
  u16* Xb  = VLb + SZ;           // [B,S,H*D]
  const size_t need_bytes = (size_t)(4 * SZ + 4 * SW) * 2;
  if (ws_size < need_bytes) return;

  conv_w4<<<1024, 256, 0, stream>>>(Wq_f, Wk_f, Wv_f, Wo_f, wqb, wkb, wvb, wob, SW / 8);

  proj_gemm<<<dim3(8, 64, 3), 256, 0, stream>>>(q_f, k_f, v_f, wqb, wkb, wvb,
                                                bq, bk, bv, Qb, Kb, VLb);

  attn_fwd<<<dim3(512), 512, 0, stream>>>(Qb, Kb, VLb, Xb);

  out_gemm<<<dim3(8, 64), 256, 0, stream>>>(Xb, wob, bo, (float*)d_out);
}